// Round 2
// baseline (1474.002 us; speedup 1.0000x reference)
//
#include <hip/hip_runtime.h>
#include <hip/hip_bf16.h>
#include <stdint.h>

#define DEV __device__ __forceinline__

typedef unsigned short u16;
typedef __bf16 bf16x8 __attribute__((ext_vector_type(8)));
typedef float f32x4 __attribute__((ext_vector_type(4)));

DEV float b2f(u16 u) { return __uint_as_float(((uint32_t)u) << 16); }
DEV u16 f2b(float f) {
  uint32_t u = __float_as_uint(f);
  u += 0x7fffu + ((u >> 16) & 1u);   // RNE
  return (u16)(u >> 16);
}
DEV float sigm(float z) { return __builtin_amdgcn_rcpf(1.f + __expf(-z)); }

// async global->LDS 16B. LDS dest is wave-uniform base + lane*16.
DEV void async16(const void* g, void* l) {
  __builtin_amdgcn_global_load_lds(
      (const __attribute__((address_space(1))) uint32_t*)g,
      (__attribute__((address_space(3))) uint32_t*)l, 16, 0, 0);
}

// ---------------- weight prep: W'[k][c]=g[k]*W[k][c]; store W'^T (permuted cols), col sums ----
__global__ void prep_w_kernel(const float* __restrict__ W, const float* __restrict__ g,
                              const float* __restrict__ bv, u16* __restrict__ Wt,
                              float* __restrict__ scol, float* __restrict__ tcol,
                              int K, int hid, int kk) {
  int c = blockIdx.x * 256 + threadIdx.x;
  int C = 2 * hid * kk;
  if (c >= C) return;
  int d = c / (hid * kk);
  int rem = c - d * hid * kk;
  int h = rem / kk;
  int j = rem - h * kk;
  int cp = (d * kk + j) * hid + h;    // permuted col: planes (d, j, h)
  float as_ = 0.f, at_ = 0.f;
  for (int k2 = 0; k2 < K; ++k2) {
    float w = W[(long long)k2 * C + c];
    float gg = g[k2];
    as_ += gg * w;
    at_ += bv[k2] * w;
    Wt[(long long)cp * K + k2] = f2b(gg * w);
  }
  scol[cp] = as_;
  tcol[cp] = at_;
}

__global__ void prep_wout_kernel(const float* __restrict__ w, u16* __restrict__ o) {
  int i = blockIdx.x * 256 + threadIdx.x;
  o[i] = f2b(w[i]);   // 64*128
}

// ---------------- embedding + LN(ng,nb) -> bf16, (n,t) row layout ----------------
__global__ __launch_bounds__(256) void emb_kernel(const int* __restrict__ x,
                                                  const float* __restrict__ emb,
                                                  const float* __restrict__ ng,
                                                  const float* __restrict__ nb,
                                                  u16* __restrict__ out) {
  int row = blockIdx.x * 4 + (threadIdx.x >> 6);  // row = n*512 + t
  int lane = threadIdx.x & 63;
  int tok = x[(row & 511) * 256 + (row >> 9)];    // x is (t, n)
  float4 v = *(const float4*)&emb[(long long)tok * 256 + lane * 4];
  float s = v.x + v.y + v.z + v.w;
  float sq = v.x * v.x + v.y * v.y + v.z * v.z + v.w * v.w;
#pragma unroll
  for (int off = 32; off; off >>= 1) { s += __shfl_xor(s, off); sq += __shfl_xor(sq, off); }
  float m = s * (1.f / 256.f);
  float var = fmaxf(sq * (1.f / 256.f) - m * m, 0.f);
  float rstd = rsqrtf(var + 1e-5f);
  float4 g = *(const float4*)&ng[lane * 4];
  float4 b = *(const float4*)&nb[lane * 4];
  ushort4 o;
  o.x = f2b((v.x - m) * rstd * g.x + b.x);
  o.y = f2b((v.y - m) * rstd * g.y + b.y);
  o.z = f2b((v.z - m) * rstd * g.z + b.z);
  o.w = f2b((v.w - m) * rstd * g.w + b.w);
  *(ushort4*)&out[(long long)row * 256 + lane * 4] = o;
}

// ---------------- per-row mean/rstd of bf16 X ----------------
template <int D>
__global__ __launch_bounds__(256) void stats_kernel(const u16* __restrict__ X,
                                                    float* __restrict__ st) {
  int row = blockIdx.x * 4 + (threadIdx.x >> 6);
  int lane = threadIdx.x & 63;
  constexpr int P = D / 64;
  const u16* xp = X + (long long)row * D + lane * P;
  float s = 0.f, sq = 0.f;
#pragma unroll
  for (int i = 0; i < P; ++i) { float v = b2f(xp[i]); s += v; sq += v * v; }
#pragma unroll
  for (int off = 32; off; off >>= 1) { s += __shfl_xor(s, off); sq += __shfl_xor(sq, off); }
  if (lane == 0) {
    float m = s * (1.f / D);
    float var = fmaxf(sq * (1.f / D) - m * m, 0.f);
    ((float2*)st)[row] = make_float2(m, rsqrtf(var + 1e-5f));
  }
}

// ---------------- GEMM: U = rstd*(X@W') - m*rstd*scol + tcol, bf16 out ----------------
// X: M x K bf16, Wt: C x K bf16 (B^T), tiles 128x128, BK=64, 4 waves.
__global__ __launch_bounds__(256) void gemm_kernel(const u16* __restrict__ X,
                                                   const u16* __restrict__ Wt,
                                                   const float* __restrict__ stats,
                                                   const float* __restrict__ scol,
                                                   const float* __restrict__ tcol,
                                                   u16* __restrict__ U, int K, int C) {
  __shared__ u16 As[128 * 64];
  __shared__ u16 Bs[128 * 64];
  const int tid = threadIdx.x;
  const int lane = tid & 63, wid = tid >> 6;
  const int la = lane & 15, lq = lane >> 4;
  const int wr = wid >> 1, wc = wid & 1;
  const long long m0 = (long long)blockIdx.x * 128;
  const int c0 = blockIdx.y * 128;

  f32x4 acc[4][4] = {};
  const int nkt = K >> 6;
  const int rsb = K * 2;  // row stride bytes

  for (int kt = 0; kt < nkt; ++kt) {
    const char* abase = (const char*)X + (m0 * K + kt * 64) * 2;
    const char* bbase = (const char*)Wt + ((long long)c0 * K + kt * 64) * 2;
#pragma unroll
    for (int it = 0; it < 4; ++it) {
      int u = it * 256 + tid;
      int row = u >> 3, q = u & 7;
      int sq_ = (q ^ (row & 7)) << 4;
      async16(abase + (long long)row * rsb + sq_, (char*)As + it * 4096 + wid * 1024);
      async16(bbase + (long long)row * rsb + sq_, (char*)Bs + it * 4096 + wid * 1024);
    }
    __syncthreads();
#pragma unroll
    for (int ks = 0; ks < 2; ++ks) {
      bf16x8 a[4], b[4];
#pragma unroll
      for (int mf = 0; mf < 4; ++mf) {
        int row = wr * 64 + mf * 16 + la;
        a[mf] = *(const bf16x8*)&As[row * 64 + ((((ks << 2) | lq) ^ (row & 7)) << 3)];
      }
#pragma unroll
      for (int nf = 0; nf < 4; ++nf) {
        int row = wc * 64 + nf * 16 + la;
        b[nf] = *(const bf16x8*)&Bs[row * 64 + ((((ks << 2) | lq) ^ (row & 7)) << 3)];
      }
#pragma unroll
      for (int mf = 0; mf < 4; ++mf)
#pragma unroll
        for (int nf = 0; nf < 4; ++nf)
          acc[mf][nf] = __builtin_amdgcn_mfma_f32_16x16x32_bf16(a[mf], b[nf], acc[mf][nf], 0, 0, 0);
    }
    __syncthreads();
  }

#pragma unroll
  for (int mf = 0; mf < 4; ++mf) {
    long long r0 = m0 + wr * 64 + mf * 16 + lq * 4;
    float2 st[4];
#pragma unroll
    for (int reg = 0; reg < 4; ++reg) st[reg] = *(const float2*)&stats[(r0 + reg) * 2];
#pragma unroll
    for (int nf = 0; nf < 4; ++nf) {
      int colg = c0 + wc * 64 + nf * 16 + la;
      float sc = scol[colg], tc = tcol[colg];
#pragma unroll
      for (int reg = 0; reg < 4; ++reg) {
        float uv = st[reg].y * acc[mf][nf][reg] - st[reg].x * st[reg].y * sc + tc;
        U[(r0 + reg) * C + colg] = f2b(uv);
      }
    }
  }
}

// ---------------- SRU scan ----------------
// (n,t) layout. U chunk: rows nloc*512+t, cols (d,j,h) planes. One thread per chain.
template <int KK, int LOGH>
__global__ __launch_bounds__(256) void scan_kernel(const u16* __restrict__ Uc,
                                                   const u16* __restrict__ X,
                                                   const float* __restrict__ stats,
                                                   const float* __restrict__ gln,
                                                   const float* __restrict__ bln,
                                                   const float* __restrict__ vv,
                                                   const float* __restrict__ bb,
                                                   u16* __restrict__ H, int n0) {
  constexpr int T = 512;
  constexpr int HID = 1 << LOGH;
  constexpr int C = 2 * KK * HID;
  constexpr int DO = 2 * HID;
  constexpr int CH = 8;

  int idx = blockIdx.x * 256 + threadIdx.x;
  int h = idx & (HID - 1);
  int d = (idx >> LOGH) & 1;
  int nloc = idx >> (LOGH + 1);
  int n = n0 + nloc;
  int col = d * HID + h;

  float vf = vv[2 * col], vr = vv[2 * col + 1];
  float bfv = bb[2 * col], brv = bb[2 * col + 1];
  float gc = 0.f, bc = 0.f;
  if (KK == 3) { gc = gln[col]; bc = bln[col]; }

  int t0 = d ? (T - 1) : 0;
  long long stp = d ? -1 : 1;
  long long ustr = stp * (long long)C;
  long long xstr = stp * (long long)DO;
  long long sstr = stp;

  const u16* Up = Uc + ((long long)nloc * T + t0) * C + d * (KK * HID) + h;
  const u16* Xp = X + ((long long)n * T + t0) * DO + col;
  const float2* Sp = (const float2*)stats + ((long long)n * T + t0);
  u16* Hp = H + ((long long)n * T + t0) * DO + col;

  u16 b0x[CH], b0f[CH], b0r[CH], b0s[CH];
  float b0m[CH], b0v[CH];
  u16 b1x[CH], b1f[CH], b1r[CH], b1s[CH];
  float b1m[CH], b1v[CH];
  float c = 0.f;

#define SCAN_LOAD(S, BX, BF, BR, BS, BM, BV)                        \
  {                                                                 \
    _Pragma("unroll") for (int i = 0; i < CH; ++i) {                \
      long long o = (long long)((S) + i) * ustr;                    \
      BX[i] = Up[o];                                                \
      BF[i] = Up[o + HID];                                          \
      BR[i] = Up[o + 2 * HID];                                      \
      if (KK == 4) {                                                \
        BS[i] = Up[o + 3 * HID];                                    \
      } else {                                                      \
        BS[i] = Xp[(long long)((S) + i) * xstr];                    \
        float2 stv = Sp[(long long)((S) + i) * sstr];               \
        BM[i] = stv.x;                                              \
        BV[i] = stv.y;                                              \
      }                                                             \
    }                                                               \
  }

#define SCAN_COMP(S, BX, BF, BR, BS, BM, BV)                        \
  {                                                                 \
    _Pragma("unroll") for (int i = 0; i < CH; ++i) {                \
      float xt = b2f(BX[i]), fr = b2f(BF[i]), rr = b2f(BR[i]);      \
      float res = (KK == 4) ? b2f(BS[i])                            \
                            : (b2f(BS[i]) - BM[i]) * BV[i] * gc + bc; \
      float ff = sigm(fr + vf * c + bfv);                           \
      float c2 = ff * c + (1.f - ff) * xt;                          \
      float rg = sigm(rr + vr * c + brv);                           \
      float hh = rg * fmaxf(c2, 0.f) + (1.f - rg) * res;            \
      c = c2;                                                       \
      Hp[(long long)((S) + i) * xstr] = f2b(hh);                    \
    }                                                               \
  }

  SCAN_LOAD(0, b0x, b0f, b0r, b0s, b0m, b0v);
  int s = 0;
  for (int it = 0; it < 31; ++it) {
    SCAN_LOAD(s + CH, b1x, b1f, b1r, b1s, b1m, b1v);
    SCAN_COMP(s, b0x, b0f, b0r, b0s, b0m, b0v);
    s += CH;
    SCAN_LOAD(s + CH, b0x, b0f, b0r, b0s, b0m, b0v);
    SCAN_COMP(s, b1x, b1f, b1r, b1s, b1m, b1v);
    s += CH;
  }
  SCAN_LOAD(s + CH, b1x, b1f, b1r, b1s, b1m, b1v);  // chunk 63
  SCAN_COMP(s, b0x, b0f, b0r, b0s, b0m, b0v);       // chunk 62
  s += CH;
  SCAN_COMP(s, b1x, b1f, b1r, b1s, b1m, b1v);       // chunk 63
#undef SCAN_LOAD
#undef SCAN_COMP
}

// ---------------- final projection: out[r, :] = h4[r, :] @ wout^T + bout (f32 out) ------
// (n,t) layout makes h4 rows == out rows. M=131072, K=128, N=64.
__global__ __launch_bounds__(256) void outgemm_kernel(const u16* __restrict__ h4,
                                                      const u16* __restrict__ wob,
                                                      const float* __restrict__ bout,
                                                      float* __restrict__ out) {
  __shared__ u16 As[128 * 128];  // 32 KiB
  int tid = threadIdx.x;
  int lane = tid & 63, wid = tid >> 6;
  int la = lane & 15, lq = lane >> 4;
  long long m0 = (long long)blockIdx.x * 128;

#pragma unroll
  for (int it = 0; it < 8; ++it) {
    int u = it * 256 + tid;
    int row = u >> 4, q = u & 15;
    const char* src = (const char*)h4 + (m0 + row) * 256 + ((q ^ (row & 7)) << 4);
    async16(src, (char*)As + it * 4096 + wid * 1024);
  }
  bf16x8 bfr[4][4];
#pragma unroll
  for (int nf = 0; nf < 4; ++nf)
#pragma unroll
    for (int ks = 0; ks < 4; ++ks)
      bfr[nf][ks] = *(const bf16x8*)&wob[(nf * 16 + la) * 128 + ks * 32 + lq * 8];
  __syncthreads();

  f32x4 acc[2][4] = {};
#pragma unroll
  for (int ks = 0; ks < 4; ++ks) {
#pragma unroll
    for (int mf = 0; mf < 2; ++mf) {
      int row = wid * 32 + mf * 16 + la;
      bf16x8 a = *(const bf16x8*)&As[row * 128 + (((ks * 4 + lq) ^ (row & 7)) << 3)];
#pragma unroll
      for (int nf = 0; nf < 4; ++nf)
        acc[mf][nf] = __builtin_amdgcn_mfma_f32_16x16x32_bf16(a, bfr[nf][ks], acc[mf][nf], 0, 0, 0);
    }
  }
#pragma unroll
  for (int mf = 0; mf < 2; ++mf)
#pragma unroll
    for (int nf = 0; nf < 4; ++nf) {
      int colg = nf * 16 + la;
      float bo = bout[colg];
#pragma unroll
      for (int reg = 0; reg < 4; ++reg) {
        long long r = m0 + wid * 32 + mf * 16 + lq * 4 + reg;
        out[r * 64 + colg] = acc[mf][nf][reg] + bo;
      }
    }
}

// ---------------- launch ----------------
extern "C" void kernel_launch(void* const* d_in, const int* in_sizes, int n_in,
                              void* d_out, int out_size, void* d_ws, size_t ws_size,
                              hipStream_t stream) {
  const int* x = (const int*)d_in[0];
  const float* emb = (const float*)d_in[1];
  const float* ng = (const float*)d_in[2];
  const float* nb = (const float*)d_in[3];
  const float* W[4] = {(const float*)d_in[4], (const float*)d_in[9], (const float*)d_in[14],
                       (const float*)d_in[19]};
  const float* Vv[4] = {(const float*)d_in[5], (const float*)d_in[10], (const float*)d_in[15],
                        (const float*)d_in[20]};
  const float* Bv[4] = {(const float*)d_in[6], (const float*)d_in[11], (const float*)d_in[16],
                        (const float*)d_in[21]};
  const float* G[4] = {(const float*)d_in[7], (const float*)d_in[12], (const float*)d_in[17],
                       (const float*)d_in[22]};
  const float* Bt[4] = {(const float*)d_in[8], (const float*)d_in[13], (const float*)d_in[18],
                        (const float*)d_in[23]};
  const float* wout = (const float*)d_in[24];
  const float* bout = (const float*)d_in[25];
  float* out = (float*)d_out;

  char* ws = (char*)d_ws;
  u16* XA = (u16*)ws;                       // 64 MiB ping
  u16* XB = (u16*)(ws + 67108864);          // 64 MiB pong
  float* stats = (float*)(ws + 134217728);  // 1 MiB
  char* p = ws + 135266304;
  u16* Wt[4];
  float* Sc[4];
  float* Tc[4];
  int Kd[4] = {256, 256, 256, 128};
  int Hd[4] = {128, 128, 64, 64};
  int kkv[4] = {3, 3, 4, 3};
  for (int i = 0; i < 4; ++i) {
    int C = 2 * Hd[i] * kkv[i];
    Wt[i] = (u16*)p; p += (size_t)C * Kd[i] * 2;
    Sc[i] = (float*)p; p += (size_t)C * 4;
    Tc[i] = (float*)p; p += (size_t)C * 4;
  }
  u16* wob = (u16*)p;                       // 32 KiB; ends < 137363456
  u16* Ubuf = (u16*)(ws + 137363456);

  // largest n-chunk NC (rows = NC*512, max C = 768) that fits in ws_size; cap 128.
  int NC = 128;
  while (NC > 4 &&
         137363456ull + (unsigned long long)NC * 512 * 768 * 2 > (unsigned long long)ws_size)
    NC >>= 1;

  for (int i = 0; i < 4; ++i) {
    int C = 2 * Hd[i] * kkv[i];
    prep_w_kernel<<<dim3((C + 255) / 256), dim3(256), 0, stream>>>(
        W[i], G[i], Bt[i], Wt[i], Sc[i], Tc[i], Kd[i], Hd[i], kkv[i]);
  }
  prep_wout_kernel<<<dim3(32), dim3(256), 0, stream>>>(wout, wob);
  emb_kernel<<<dim3(32768), dim3(256), 0, stream>>>(x, emb, ng, nb, XA);

  // L1: XA -> XB  (K=256, C=768, HID=128, kk=3)
  stats_kernel<256><<<dim3(32768), dim3(256), 0, stream>>>(XA, stats);
  for (int c = 0; c < 256; c += NC) {
    gemm_kernel<<<dim3(NC * 4, 6), dim3(256), 0, stream>>>(
        XA + (size_t)c * 512 * 256, Wt[0], stats + (size_t)c * 512 * 2, Sc[0], Tc[0], Ubuf, 256, 768);
    scan_kernel<3, 7><<<dim3(NC), dim3(256), 0, stream>>>(
        Ubuf, XA, stats, G[0], Bt[0], Vv[0], Bv[0], XB, c);
  }
  // L2: XB -> XA
  stats_kernel<256><<<dim3(32768), dim3(256), 0, stream>>>(XB, stats);
  for (int c = 0; c < 256; c += NC) {
    gemm_kernel<<<dim3(NC * 4, 6), dim3(256), 0, stream>>>(
        XB + (size_t)c * 512 * 256, Wt[1], stats + (size_t)c * 512 * 2, Sc[1], Tc[1], Ubuf, 256, 768);
    scan_kernel<3, 7><<<dim3(NC), dim3(256), 0, stream>>>(
        Ubuf, XB, stats, G[1], Bt[1], Vv[1], Bv[1], XA, c);
  }
  // L3: XA -> XB  (K=256, C=512, HID=64, kk=4: res from U plane 3)
  stats_kernel<256><<<dim3(32768), dim3(256), 0, stream>>>(XA, stats);
  for (int c = 0; c < 256; c += NC) {
    gemm_kernel<<<dim3(NC * 4, 4), dim3(256), 0, stream>>>(
        XA + (size_t)c * 512 * 256, Wt[2], stats + (size_t)c * 512 * 2, Sc[2], Tc[2], Ubuf, 256, 512);
    scan_kernel<4, 6><<<dim3(NC / 2), dim3(256), 0, stream>>>(
        Ubuf, Ubuf, stats, G[2], Bt[2], Vv[2], Bv[2], XB, c);
  }
  // L4: XB -> XA  (K=128, C=384, HID=64, kk=3)
  stats_kernel<128><<<dim3(32768), dim3(256), 0, stream>>>(XB, stats);
  for (int c = 0; c < 256; c += NC) {
    gemm_kernel<<<dim3(NC * 4, 3), dim3(256), 0, stream>>>(
        XB + (size_t)c * 512 * 128, Wt[3], stats + (size_t)c * 512 * 2, Sc[3], Tc[3], Ubuf, 128, 384);
    scan_kernel<3, 6><<<dim3(NC / 2), dim3(256), 0, stream>>>(
        Ubuf, XB, stats, G[3], Bt[3], Vv[3], Bv[3], XA, c);
  }
  // output projection
  outgemm_kernel<<<dim3(1024), dim3(256), 0, stream>>>(XA, wob, bout, out);
}

// Round 3
// 1060.001 us; speedup vs baseline: 1.3906x; 1.3906x over previous
//
#include <hip/hip_runtime.h>
#include <hip/hip_bf16.h>
#include <stdint.h>

#define DEV __device__ __forceinline__

typedef unsigned short u16;
typedef __bf16 bf16x8 __attribute__((ext_vector_type(8)));
typedef float f32x4 __attribute__((ext_vector_type(4)));

DEV float b2f(u16 u) { return __uint_as_float(((uint32_t)u) << 16); }
DEV u16 f2b(float f) {
  uint32_t u = __float_as_uint(f);
  u += 0x7fffu + ((u >> 16) & 1u);   // RNE
  return (u16)(u >> 16);
}
DEV float sigm(float z) { return __builtin_amdgcn_rcpf(1.f + __expf(-z)); }

// async global->LDS 16B. LDS dest is wave-uniform base + lane*16.
DEV void async16(const void* g, void* l) {
  __builtin_amdgcn_global_load_lds(
      (const __attribute__((address_space(1))) uint32_t*)g,
      (__attribute__((address_space(3))) uint32_t*)l, 16, 0, 0);
}

// ---------------- weight prep: W'[k][c]=g[k]*W[k][c]; store W'^T (permuted cols), col sums ----
// One block per permuted output column; K threads over k2. Coalesced Wt writes,
// block-reduce for scol/tcol.
template <int K>
__global__ __launch_bounds__(256) void prep_w_kernel(const float* __restrict__ W,
                                                     const float* __restrict__ g,
                                                     const float* __restrict__ bv,
                                                     u16* __restrict__ Wt,
                                                     float* __restrict__ scol,
                                                     float* __restrict__ tcol,
                                                     int hid, int kk) {
  int c = blockIdx.x;
  int C = gridDim.x;          // 2*hid*kk
  int k2 = threadIdx.x;       // 0..K-1
  int d = c / (hid * kk);
  int rem = c - d * hid * kk;
  int h = rem / kk;
  int j = rem - h * kk;
  int cp = (d * kk + j) * hid + h;  // permuted col: planes (d, j, h)

  float w = W[(long long)k2 * C + c];
  float gg = g[k2];
  float a = gg * w;
  float t = bv[k2] * w;
  Wt[(long long)cp * K + k2] = f2b(a);

#pragma unroll
  for (int off = 32; off; off >>= 1) { a += __shfl_xor(a, off); t += __shfl_xor(t, off); }
  __shared__ float sa[4], stt[4];
  int wv = threadIdx.x >> 6, ln = threadIdx.x & 63;
  if (ln == 0) { sa[wv] = a; stt[wv] = t; }
  __syncthreads();
  if (threadIdx.x == 0) {
    float A = 0.f, T = 0.f;
#pragma unroll
    for (int i = 0; i < K / 64; ++i) { A += sa[i]; T += stt[i]; }
    scol[cp] = A;
    tcol[cp] = T;
  }
}

__global__ void prep_wout_kernel(const float* __restrict__ w, u16* __restrict__ o) {
  int i = blockIdx.x * 256 + threadIdx.x;
  o[i] = f2b(w[i]);   // 64*128
}

// ---------------- embedding + LN(ng,nb) -> bf16, (n,t) row layout ----------------
__global__ __launch_bounds__(256) void emb_kernel(const int* __restrict__ x,
                                                  const float* __restrict__ emb,
                                                  const float* __restrict__ ng,
                                                  const float* __restrict__ nb,
                                                  u16* __restrict__ out) {
  int row = blockIdx.x * 4 + (threadIdx.x >> 6);  // row = n*512 + t
  int lane = threadIdx.x & 63;
  int tok = x[(row & 511) * 256 + (row >> 9)];    // x is (t, n)
  float4 v = *(const float4*)&emb[(long long)tok * 256 + lane * 4];
  float s = v.x + v.y + v.z + v.w;
  float sq = v.x * v.x + v.y * v.y + v.z * v.z + v.w * v.w;
#pragma unroll
  for (int off = 32; off; off >>= 1) { s += __shfl_xor(s, off); sq += __shfl_xor(sq, off); }
  float m = s * (1.f / 256.f);
  float var = fmaxf(sq * (1.f / 256.f) - m * m, 0.f);
  float rstd = rsqrtf(var + 1e-5f);
  float4 g = *(const float4*)&ng[lane * 4];
  float4 b = *(const float4*)&nb[lane * 4];
  ushort4 o;
  o.x = f2b((v.x - m) * rstd * g.x + b.x);
  o.y = f2b((v.y - m) * rstd * g.y + b.y);
  o.z = f2b((v.z - m) * rstd * g.z + b.z);
  o.w = f2b((v.w - m) * rstd * g.w + b.w);
  *(ushort4*)&out[(long long)row * 256 + lane * 4] = o;
}

// ---------------- per-row mean/rstd of bf16 X ----------------
template <int D>
__global__ __launch_bounds__(256) void stats_kernel(const u16* __restrict__ X,
                                                    float* __restrict__ st) {
  int row = blockIdx.x * 4 + (threadIdx.x >> 6);
  int lane = threadIdx.x & 63;
  constexpr int P = D / 64;
  const u16* xp = X + (long long)row * D + lane * P;
  float s = 0.f, sq = 0.f;
#pragma unroll
  for (int i = 0; i < P; ++i) { float v = b2f(xp[i]); s += v; sq += v * v; }
#pragma unroll
  for (int off = 32; off; off >>= 1) { s += __shfl_xor(s, off); sq += __shfl_xor(sq, off); }
  if (lane == 0) {
    float m = s * (1.f / D);
    float var = fmaxf(sq * (1.f / D) - m * m, 0.f);
    ((float2*)st)[row] = make_float2(m, rsqrtf(var + 1e-5f));
  }
}

// ---------------- GEMM: U = rstd*(X@W') - m*rstd*scol + tcol, bf16 out ----------------
// X: M x K bf16, Wt: C x K bf16 (B^T), tiles 128x128, BK=64, 4 waves.
__global__ __launch_bounds__(256) void gemm_kernel(const u16* __restrict__ X,
                                                   const u16* __restrict__ Wt,
                                                   const float* __restrict__ stats,
                                                   const float* __restrict__ scol,
                                                   const float* __restrict__ tcol,
                                                   u16* __restrict__ U, int K, int C) {
  __shared__ u16 As[128 * 64];
  __shared__ u16 Bs[128 * 64];
  const int tid = threadIdx.x;
  const int lane = tid & 63, wid = tid >> 6;
  const int la = lane & 15, lq = lane >> 4;
  const int wr = wid >> 1, wc = wid & 1;
  const long long m0 = (long long)blockIdx.x * 128;
  const int c0 = blockIdx.y * 128;

  f32x4 acc[4][4] = {};
  const int nkt = K >> 6;
  const int rsb = K * 2;  // row stride bytes

  for (int kt = 0; kt < nkt; ++kt) {
    const char* abase = (const char*)X + (m0 * K + kt * 64) * 2;
    const char* bbase = (const char*)Wt + ((long long)c0 * K + kt * 64) * 2;
#pragma unroll
    for (int it = 0; it < 4; ++it) {
      int u = it * 256 + tid;
      int row = u >> 3, q = u & 7;
      int sq_ = (q ^ (row & 7)) << 4;
      async16(abase + (long long)row * rsb + sq_, (char*)As + it * 4096 + wid * 1024);
      async16(bbase + (long long)row * rsb + sq_, (char*)Bs + it * 4096 + wid * 1024);
    }
    __syncthreads();
#pragma unroll
    for (int ks = 0; ks < 2; ++ks) {
      bf16x8 a[4], b[4];
#pragma unroll
      for (int mf = 0; mf < 4; ++mf) {
        int row = wr * 64 + mf * 16 + la;
        a[mf] = *(const bf16x8*)&As[row * 64 + ((((ks << 2) | lq) ^ (row & 7)) << 3)];
      }
#pragma unroll
      for (int nf = 0; nf < 4; ++nf) {
        int row = wc * 64 + nf * 16 + la;
        b[nf] = *(const bf16x8*)&Bs[row * 64 + ((((ks << 2) | lq) ^ (row & 7)) << 3)];
      }
#pragma unroll
      for (int mf = 0; mf < 4; ++mf)
#pragma unroll
        for (int nf = 0; nf < 4; ++nf)
          acc[mf][nf] = __builtin_amdgcn_mfma_f32_16x16x32_bf16(a[mf], b[nf], acc[mf][nf], 0, 0, 0);
    }
    __syncthreads();
  }

#pragma unroll
  for (int mf = 0; mf < 4; ++mf) {
    long long r0 = m0 + wr * 64 + mf * 16 + lq * 4;
    float2 st[4];
#pragma unroll
    for (int reg = 0; reg < 4; ++reg) st[reg] = *(const float2*)&stats[(r0 + reg) * 2];
#pragma unroll
    for (int nf = 0; nf < 4; ++nf) {
      int colg = c0 + wc * 64 + nf * 16 + la;
      float sc = scol[colg], tc = tcol[colg];
#pragma unroll
      for (int reg = 0; reg < 4; ++reg) {
        float uv = st[reg].y * acc[mf][nf][reg] - st[reg].x * st[reg].y * sc + tc;
        U[(r0 + reg) * C + colg] = f2b(uv);
      }
    }
  }
}

// ---------------- SRU scan ----------------
// (n,t) layout. U chunk: rows nloc*512+t, cols (d,j,h) planes. One thread per chain.
template <int KK, int LOGH>
__global__ __launch_bounds__(256) void scan_kernel(const u16* __restrict__ Uc,
                                                   const u16* __restrict__ X,
                                                   const float* __restrict__ stats,
                                                   const float* __restrict__ gln,
                                                   const float* __restrict__ bln,
                                                   const float* __restrict__ vv,
                                                   const float* __restrict__ bb,
                                                   u16* __restrict__ H, int n0) {
  constexpr int T = 512;
  constexpr int HID = 1 << LOGH;
  constexpr int C = 2 * KK * HID;
  constexpr int DO = 2 * HID;
  constexpr int CH = 8;

  int idx = blockIdx.x * 256 + threadIdx.x;
  int h = idx & (HID - 1);
  int d = (idx >> LOGH) & 1;
  int nloc = idx >> (LOGH + 1);
  int n = n0 + nloc;
  int col = d * HID + h;

  float vf = vv[2 * col], vr = vv[2 * col + 1];
  float bfv = bb[2 * col], brv = bb[2 * col + 1];
  float gc = 0.f, bc = 0.f;
  if (KK == 3) { gc = gln[col]; bc = bln[col]; }

  int t0 = d ? (T - 1) : 0;
  long long stp = d ? -1 : 1;
  long long ustr = stp * (long long)C;
  long long xstr = stp * (long long)DO;
  long long sstr = stp;

  const u16* Up = Uc + ((long long)nloc * T + t0) * C + d * (KK * HID) + h;
  const u16* Xp = X + ((long long)n * T + t0) * DO + col;
  const float2* Sp = (const float2*)stats + ((long long)n * T + t0);
  u16* Hp = H + ((long long)n * T + t0) * DO + col;

  u16 b0x[CH], b0f[CH], b0r[CH], b0s[CH];
  float b0m[CH], b0v[CH];
  u16 b1x[CH], b1f[CH], b1r[CH], b1s[CH];
  float b1m[CH], b1v[CH];
  float c = 0.f;

#define SCAN_LOAD(S, BX, BF, BR, BS, BM, BV)                        \
  {                                                                 \
    _Pragma("unroll") for (int i = 0; i < CH; ++i) {                \
      long long o = (long long)((S) + i) * ustr;                    \
      BX[i] = Up[o];                                                \
      BF[i] = Up[o + HID];                                          \
      BR[i] = Up[o + 2 * HID];                                      \
      if (KK == 4) {                                                \
        BS[i] = Up[o + 3 * HID];                                    \
      } else {                                                      \
        BS[i] = Xp[(long long)((S) + i) * xstr];                    \
        float2 stv = Sp[(long long)((S) + i) * sstr];               \
        BM[i] = stv.x;                                              \
        BV[i] = stv.y;                                              \
      }                                                             \
    }                                                               \
  }

#define SCAN_COMP(S, BX, BF, BR, BS, BM, BV)                        \
  {                                                                 \
    _Pragma("unroll") for (int i = 0; i < CH; ++i) {                \
      float xt = b2f(BX[i]), fr = b2f(BF[i]), rr = b2f(BR[i]);      \
      float res = (KK == 4) ? b2f(BS[i])                            \
                            : (b2f(BS[i]) - BM[i]) * BV[i] * gc + bc; \
      float ff = sigm(fr + vf * c + bfv);                           \
      float c2 = ff * c + (1.f - ff) * xt;                          \
      float rg = sigm(rr + vr * c + brv);                           \
      float hh = rg * fmaxf(c2, 0.f) + (1.f - rg) * res;            \
      c = c2;                                                       \
      Hp[(long long)((S) + i) * xstr] = f2b(hh);                    \
    }                                                               \
  }

  SCAN_LOAD(0, b0x, b0f, b0r, b0s, b0m, b0v);
  int s = 0;
  for (int it = 0; it < 31; ++it) {
    SCAN_LOAD(s + CH, b1x, b1f, b1r, b1s, b1m, b1v);
    SCAN_COMP(s, b0x, b0f, b0r, b0s, b0m, b0v);
    s += CH;
    SCAN_LOAD(s + CH, b0x, b0f, b0r, b0s, b0m, b0v);
    SCAN_COMP(s, b1x, b1f, b1r, b1s, b1m, b1v);
    s += CH;
  }
  SCAN_LOAD(s + CH, b1x, b1f, b1r, b1s, b1m, b1v);  // chunk 63
  SCAN_COMP(s, b0x, b0f, b0r, b0s, b0m, b0v);       // chunk 62
  s += CH;
  SCAN_COMP(s, b1x, b1f, b1r, b1s, b1m, b1v);       // chunk 63
#undef SCAN_LOAD
#undef SCAN_COMP
}

// ---------------- final projection: out[r, :] = h4[r, :] @ wout^T + bout (f32 out) ------
// (n,t) layout makes h4 rows == out rows. M=131072, K=128, N=64.
__global__ __launch_bounds__(256) void outgemm_kernel(const u16* __restrict__ h4,
                                                      const u16* __restrict__ wob,
                                                      const float* __restrict__ bout,
                                                      float* __restrict__ out) {
  __shared__ u16 As[128 * 128];  // 32 KiB
  int tid = threadIdx.x;
  int lane = tid & 63, wid = tid >> 6;
  int la = lane & 15, lq = lane >> 4;
  long long m0 = (long long)blockIdx.x * 128;

#pragma unroll
  for (int it = 0; it < 8; ++it) {
    int u = it * 256 + tid;
    int row = u >> 4, q = u & 15;
    const char* src = (const char*)h4 + (m0 + row) * 256 + ((q ^ (row & 7)) << 4);
    async16(src, (char*)As + it * 4096 + wid * 1024);
  }
  bf16x8 bfr[4][4];
#pragma unroll
  for (int nf = 0; nf < 4; ++nf)
#pragma unroll
    for (int ks = 0; ks < 4; ++ks)
      bfr[nf][ks] = *(const bf16x8*)&wob[(nf * 16 + la) * 128 + ks * 32 + lq * 8];
  __syncthreads();

  f32x4 acc[2][4] = {};
#pragma unroll
  for (int ks = 0; ks < 4; ++ks) {
#pragma unroll
    for (int mf = 0; mf < 2; ++mf) {
      int row = wid * 32 + mf * 16 + la;
      bf16x8 a = *(const bf16x8*)&As[row * 128 + (((ks * 4 + lq) ^ (row & 7)) << 3)];
#pragma unroll
      for (int nf = 0; nf < 4; ++nf)
        acc[mf][nf] = __builtin_amdgcn_mfma_f32_16x16x32_bf16(a, bfr[nf][ks], acc[mf][nf], 0, 0, 0);
    }
  }
#pragma unroll
  for (int mf = 0; mf < 2; ++mf)
#pragma unroll
    for (int nf = 0; nf < 4; ++nf) {
      int colg = nf * 16 + la;
      float bo = bout[colg];
#pragma unroll
      for (int reg = 0; reg < 4; ++reg) {
        long long r = m0 + wid * 32 + mf * 16 + lq * 4 + reg;
        out[r * 64 + colg] = acc[mf][nf][reg] + bo;
      }
    }
}

// ---------------- launch ----------------
extern "C" void kernel_launch(void* const* d_in, const int* in_sizes, int n_in,
                              void* d_out, int out_size, void* d_ws, size_t ws_size,
                              hipStream_t stream) {
  const int* x = (const int*)d_in[0];
  const float* emb = (const float*)d_in[1];
  const float* ng = (const float*)d_in[2];
  const float* nb = (const float*)d_in[3];
  const float* W[4] = {(const float*)d_in[4], (const float*)d_in[9], (const float*)d_in[14],
                       (const float*)d_in[19]};
  const float* Vv[4] = {(const float*)d_in[5], (const float*)d_in[10], (const float*)d_in[15],
                        (const float*)d_in[20]};
  const float* Bv[4] = {(const float*)d_in[6], (const float*)d_in[11], (const float*)d_in[16],
                        (const float*)d_in[21]};
  const float* G[4] = {(const float*)d_in[7], (const float*)d_in[12], (const float*)d_in[17],
                       (const float*)d_in[22]};
  const float* Bt[4] = {(const float*)d_in[8], (const float*)d_in[13], (const float*)d_in[18],
                        (const float*)d_in[23]};
  const float* wout = (const float*)d_in[24];
  const float* bout = (const float*)d_in[25];
  float* out = (float*)d_out;

  char* ws = (char*)d_ws;
  u16* XA = (u16*)ws;                       // 64 MiB ping
  u16* XB = (u16*)(ws + 67108864);          // 64 MiB pong
  float* stats = (float*)(ws + 134217728);  // 1 MiB
  char* p = ws + 135266304;
  u16* Wt[4];
  float* Sc[4];
  float* Tc[4];
  int Kd[4] = {256, 256, 256, 128};
  int Hd[4] = {128, 128, 64, 64};
  int kkv[4] = {3, 3, 4, 3};
  for (int i = 0; i < 4; ++i) {
    int C = 2 * Hd[i] * kkv[i];
    Wt[i] = (u16*)p; p += (size_t)C * Kd[i] * 2;
    Sc[i] = (float*)p; p += (size_t)C * 4;
    Tc[i] = (float*)p; p += (size_t)C * 4;
  }
  u16* wob = (u16*)p;                       // 32 KiB; ends < 137363456
  u16* Ubuf = (u16*)(ws + 137363456);

  // largest n-chunk NC (rows = NC*512, max C = 768) that fits in ws_size; cap 256.
  int NC = 256;
  while (NC > 4 &&
         137363456ull + (unsigned long long)NC * 512 * 768 * 2 > (unsigned long long)ws_size)
    NC >>= 1;

  for (int i = 0; i < 3; ++i) {
    int C = 2 * Hd[i] * kkv[i];
    prep_w_kernel<256><<<dim3(C), dim3(256), 0, stream>>>(
        W[i], G[i], Bt[i], Wt[i], Sc[i], Tc[i], Hd[i], kkv[i]);
  }
  prep_w_kernel<128><<<dim3(384), dim3(128), 0, stream>>>(
      W[3], G[3], Bt[3], Wt[3], Sc[3], Tc[3], Hd[3], kkv[3]);
  prep_wout_kernel<<<dim3(32), dim3(256), 0, stream>>>(wout, wob);
  emb_kernel<<<dim3(32768), dim3(256), 0, stream>>>(x, emb, ng, nb, XA);

  // L1: XA -> XB  (K=256, C=768, HID=128, kk=3)
  stats_kernel<256><<<dim3(32768), dim3(256), 0, stream>>>(XA, stats);
  for (int c = 0; c < 256; c += NC) {
    gemm_kernel<<<dim3(NC * 4, 6), dim3(256), 0, stream>>>(
        XA + (size_t)c * 512 * 256, Wt[0], stats + (size_t)c * 512 * 2, Sc[0], Tc[0], Ubuf, 256, 768);
    scan_kernel<3, 7><<<dim3(NC), dim3(256), 0, stream>>>(
        Ubuf, XA, stats, G[0], Bt[0], Vv[0], Bv[0], XB, c);
  }
  // L2: XB -> XA
  stats_kernel<256><<<dim3(32768), dim3(256), 0, stream>>>(XB, stats);
  for (int c = 0; c < 256; c += NC) {
    gemm_kernel<<<dim3(NC * 4, 6), dim3(256), 0, stream>>>(
        XB + (size_t)c * 512 * 256, Wt[1], stats + (size_t)c * 512 * 2, Sc[1], Tc[1], Ubuf, 256, 768);
    scan_kernel<3, 7><<<dim3(NC), dim3(256), 0, stream>>>(
        Ubuf, XB, stats, G[1], Bt[1], Vv[1], Bv[1], XA, c);
  }
  // L3: XA -> XB  (K=256, C=512, HID=64, kk=4: res from U plane 3)
  stats_kernel<256><<<dim3(32768), dim3(256), 0, stream>>>(XA, stats);
  for (int c = 0; c < 256; c += NC) {
    gemm_kernel<<<dim3(NC * 4, 4), dim3(256), 0, stream>>>(
        XA + (size_t)c * 512 * 256, Wt[2], stats + (size_t)c * 512 * 2, Sc[2], Tc[2], Ubuf, 256, 512);
    scan_kernel<4, 6><<<dim3(NC / 2), dim3(256), 0, stream>>>(
        Ubuf, Ubuf, stats, G[2], Bt[2], Vv[2], Bv[2], XB, c);
  }
  // L4: XB -> XA  (K=128, C=384, HID=64, kk=3)
  stats_kernel<128><<<dim3(32768), dim3(256), 0, stream>>>(XB, stats);
  for (int c = 0; c < 256; c += NC) {
    gemm_kernel<<<dim3(NC * 4, 3), dim3(256), 0, stream>>>(
        XB + (size_t)c * 512 * 128, Wt[3], stats + (size_t)c * 512 * 2, Sc[3], Tc[3], Ubuf, 128, 384);
    scan_kernel<3, 6><<<dim3(NC / 2), dim3(256), 0, stream>>>(
        Ubuf, XB, stats, G[3], Bt[3], Vv[3], Bv[3], XA, c);
  }
  // output projection
  outgemm_kernel<<<dim3(1024), dim3(256), 0, stream>>>(XA, wob, bout, out);
}

// Round 4
// 979.491 us; speedup vs baseline: 1.5049x; 1.0822x over previous
//
#include <hip/hip_runtime.h>
#include <hip/hip_bf16.h>
#include <stdint.h>

#define DEV __device__ __forceinline__

typedef unsigned short u16;
typedef __bf16 bf16x8 __attribute__((ext_vector_type(8)));
typedef float f32x4 __attribute__((ext_vector_type(4)));

DEV float b2f(u16 u) { return __uint_as_float(((uint32_t)u) << 16); }
DEV u16 f2b(float f) {
  uint32_t u = __float_as_uint(f);
  u += 0x7fffu + ((u >> 16) & 1u);   // RNE
  return (u16)(u >> 16);
}
DEV float sigm(float z) { return __builtin_amdgcn_rcpf(1.f + __expf(-z)); }

// async global->LDS 16B. LDS dest is wave-uniform base + lane*16.
DEV void async16(const void* g, void* l) {
  __builtin_amdgcn_global_load_lds(
      (const __attribute__((address_space(1))) uint32_t*)g,
      (__attribute__((address_space(3))) uint32_t*)l, 16, 0, 0);
}

// ---------------- fused weight prep for all 4 layers + wout ----------------
// blocks [0,768) L1, [768,1536) L2, [1536,2048) L3, [2048,2432) L4, [2432,2464) wout.
// Per column block: W'[k][c]=g[k]*W[k][c]; store W'^T at permuted col (d,j,h planes);
// scol=sum_k g*W, tcol=sum_k bv*W.
__global__ __launch_bounds__(256) void prep_all_kernel(
    const float* __restrict__ W0, const float* __restrict__ W1,
    const float* __restrict__ W2, const float* __restrict__ W3,
    const float* __restrict__ g0, const float* __restrict__ g1,
    const float* __restrict__ g2, const float* __restrict__ g3,
    const float* __restrict__ b0, const float* __restrict__ b1,
    const float* __restrict__ b2, const float* __restrict__ b3,
    const float* __restrict__ wout,
    u16* __restrict__ Wt0, u16* __restrict__ Wt1, u16* __restrict__ Wt2,
    u16* __restrict__ Wt3,
    float* __restrict__ Sc0, float* __restrict__ Sc1, float* __restrict__ Sc2,
    float* __restrict__ Sc3,
    float* __restrict__ Tc0, float* __restrict__ Tc1, float* __restrict__ Tc2,
    float* __restrict__ Tc3,
    u16* __restrict__ wob) {
  int b = blockIdx.x;
  if (b >= 2432) {  // wout: 64*128 = 8192 elems
    int i = (b - 2432) * 256 + threadIdx.x;
    wob[i] = f2b(wout[i]);
    return;
  }
  const float *W, *g, *bv;
  u16* Wt;
  float *scol, *tcol;
  int K, hid, kk, c;
  if (b < 768) {
    W = W0; g = g0; bv = b0; Wt = Wt0; scol = Sc0; tcol = Tc0;
    K = 256; hid = 128; kk = 3; c = b;
  } else if (b < 1536) {
    W = W1; g = g1; bv = b1; Wt = Wt1; scol = Sc1; tcol = Tc1;
    K = 256; hid = 128; kk = 3; c = b - 768;
  } else if (b < 2048) {
    W = W2; g = g2; bv = b2; Wt = Wt2; scol = Sc2; tcol = Tc2;
    K = 256; hid = 64; kk = 4; c = b - 1536;
  } else {
    W = W3; g = g3; bv = b3; Wt = Wt3; scol = Sc3; tcol = Tc3;
    K = 128; hid = 64; kk = 3; c = b - 2048;
  }
  int C = 2 * hid * kk;
  int d = c / (hid * kk);
  int rem = c - d * hid * kk;
  int h = rem / kk;
  int j = rem - h * kk;
  int cp = (d * kk + j) * hid + h;  // permuted col: planes (d, j, h)

  int k2 = threadIdx.x;
  float a = 0.f, t = 0.f;
  if (k2 < K) {
    float w = W[(long long)k2 * C + c];
    float gg = g[k2];
    a = gg * w;
    t = bv[k2] * w;
    Wt[(long long)cp * K + k2] = f2b(a);
  }
#pragma unroll
  for (int off = 32; off; off >>= 1) { a += __shfl_xor(a, off); t += __shfl_xor(t, off); }
  __shared__ float sa[4], stt[4];
  int wv = threadIdx.x >> 6, ln = threadIdx.x & 63;
  if (ln == 0 && k2 < K) { sa[wv] = a; stt[wv] = t; }
  __syncthreads();
  if (threadIdx.x == 0) {
    float A = 0.f, T = 0.f;
    int nw = K >> 6;
    for (int i = 0; i < nw; ++i) { A += sa[i]; T += stt[i]; }
    scol[cp] = A;
    tcol[cp] = T;
  }
}

// ---------------- embedding + LN(ng,nb) -> bf16, (n,t) row layout ----------------
__global__ __launch_bounds__(256) void emb_kernel(const int* __restrict__ x,
                                                  const float* __restrict__ emb,
                                                  const float* __restrict__ ng,
                                                  const float* __restrict__ nb,
                                                  u16* __restrict__ out) {
  int row = blockIdx.x * 4 + (threadIdx.x >> 6);  // row = n*512 + t
  int lane = threadIdx.x & 63;
  int tok = x[(row & 511) * 256 + (row >> 9)];    // x is (t, n)
  float4 v = *(const float4*)&emb[(long long)tok * 256 + lane * 4];
  float s = v.x + v.y + v.z + v.w;
  float sq = v.x * v.x + v.y * v.y + v.z * v.z + v.w * v.w;
#pragma unroll
  for (int off = 32; off; off >>= 1) { s += __shfl_xor(s, off); sq += __shfl_xor(sq, off); }
  float m = s * (1.f / 256.f);
  float var = fmaxf(sq * (1.f / 256.f) - m * m, 0.f);
  float rstd = rsqrtf(var + 1e-5f);
  float4 g = *(const float4*)&ng[lane * 4];
  float4 b = *(const float4*)&nb[lane * 4];
  ushort4 o;
  o.x = f2b((v.x - m) * rstd * g.x + b.x);
  o.y = f2b((v.y - m) * rstd * g.y + b.y);
  o.z = f2b((v.z - m) * rstd * g.z + b.z);
  o.w = f2b((v.w - m) * rstd * g.w + b.w);
  *(ushort4*)&out[(long long)row * 256 + lane * 4] = o;
}

// ---------------- GEMM with fused row-stats ----------------
// U = rstd*(X@W') - m*rstd*scol + tcol, bf16 out.
// X: M x K bf16, Wt: C x K bf16 (B^T), tiles 128x128, BK=64, 4 waves.
// Row mean/rstd computed in-kernel from staged LDS tiles; blockIdx.y==0 writes stats.
__global__ __launch_bounds__(256) void gemm_kernel(const u16* __restrict__ X,
                                                   const u16* __restrict__ Wt,
                                                   float* __restrict__ statsOut,
                                                   const float* __restrict__ scol,
                                                   const float* __restrict__ tcol,
                                                   u16* __restrict__ U, int K, int C) {
  __shared__ u16 As[128 * 64];
  __shared__ u16 Bs[128 * 64];
  __shared__ float sm[128], sv[128];
  const int tid = threadIdx.x;
  const int lane = tid & 63, wid = tid >> 6;
  const int la = lane & 15, lq = lane >> 4;
  const int wr = wid >> 1, wc = wid & 1;
  const long long m0 = (long long)blockIdx.x * 128;
  const int c0 = blockIdx.y * 128;

  f32x4 acc[4][4] = {};
  float ssum = 0.f, ssq = 0.f;
  const int nkt = K >> 6;
  const int rsb = K * 2;  // row stride bytes
  const int srow = tid >> 1, sq0 = (tid & 1) * 4;

  for (int kt = 0; kt < nkt; ++kt) {
    const char* abase = (const char*)X + (m0 * K + kt * 64) * 2;
    const char* bbase = (const char*)Wt + ((long long)c0 * K + kt * 64) * 2;
#pragma unroll
    for (int it = 0; it < 4; ++it) {
      int u = it * 256 + tid;
      int row = u >> 3, q = u & 7;
      int sq_ = (q ^ (row & 7)) << 4;
      async16(abase + (long long)row * rsb + sq_, (char*)As + it * 4096 + wid * 1024);
      async16(bbase + (long long)row * rsb + sq_, (char*)Bs + it * 4096 + wid * 1024);
    }
    __syncthreads();
    // row-stats partial: thread owns row tid>>1, granules (tid&1)*4..+4 (swizzle-invariant sum)
#pragma unroll
    for (int qi = 0; qi < 4; ++qi) {
      bf16x8 v = *(const bf16x8*)&As[srow * 64 + (((sq0 + qi) ^ (srow & 7)) << 3)];
#pragma unroll
      for (int e = 0; e < 8; ++e) {
        float f = (float)v[e];
        ssum += f;
        ssq += f * f;
      }
    }
#pragma unroll
    for (int ks = 0; ks < 2; ++ks) {
      bf16x8 a[4], b[4];
#pragma unroll
      for (int mf = 0; mf < 4; ++mf) {
        int row = wr * 64 + mf * 16 + la;
        a[mf] = *(const bf16x8*)&As[row * 64 + ((((ks << 2) | lq) ^ (row & 7)) << 3)];
      }
#pragma unroll
      for (int nf = 0; nf < 4; ++nf) {
        int row = wc * 64 + nf * 16 + la;
        b[nf] = *(const bf16x8*)&Bs[row * 64 + ((((ks << 2) | lq) ^ (row & 7)) << 3)];
      }
#pragma unroll
      for (int mf = 0; mf < 4; ++mf)
#pragma unroll
        for (int nf = 0; nf < 4; ++nf)
          acc[mf][nf] = __builtin_amdgcn_mfma_f32_16x16x32_bf16(a[mf], b[nf], acc[mf][nf], 0, 0, 0);
    }
    __syncthreads();
  }

  // finalize stats: combine (tid, tid^1) halves of row tid>>1
  ssum += __shfl_xor(ssum, 1);
  ssq += __shfl_xor(ssq, 1);
  if ((tid & 1) == 0) {
    float rk = 1.f / (float)K;
    float m = ssum * rk;
    float var = fmaxf(ssq * rk - m * m, 0.f);
    float rs = rsqrtf(var + 1e-5f);
    sm[srow] = m;
    sv[srow] = rs;
    if (blockIdx.y == 0) ((float2*)statsOut)[m0 + srow] = make_float2(m, rs);
  }
  __syncthreads();

#pragma unroll
  for (int mf = 0; mf < 4; ++mf) {
    int lr0 = wr * 64 + mf * 16 + lq * 4;
    long long r0 = m0 + lr0;
#pragma unroll
    for (int nf = 0; nf < 4; ++nf) {
      int colg = c0 + wc * 64 + nf * 16 + la;
      float sc = scol[colg], tc = tcol[colg];
#pragma unroll
      for (int reg = 0; reg < 4; ++reg) {
        float uv = sv[lr0 + reg] * acc[mf][nf][reg] - sm[lr0 + reg] * sv[lr0 + reg] * sc + tc;
        U[(r0 + reg) * C + colg] = f2b(uv);
      }
    }
  }
}

// ---------------- SRU scan ----------------
// (n,t) layout. One n per block; block = 2*HID threads. U chunk rows = blockIdx*512+t,
// cols in (d,j,h) planes. One thread per chain, 8-step double-buffered prefetch.
template <int KK, int LOGH>
__global__ __launch_bounds__(256) void scan_kernel(const u16* __restrict__ Uc,
                                                   const u16* __restrict__ X,
                                                   const float* __restrict__ stats,
                                                   const float* __restrict__ gln,
                                                   const float* __restrict__ bln,
                                                   const float* __restrict__ vv,
                                                   const float* __restrict__ bb,
                                                   u16* __restrict__ H, int n0) {
  constexpr int T = 512;
  constexpr int HID = 1 << LOGH;
  constexpr int C = 2 * KK * HID;
  constexpr int DO = 2 * HID;
  constexpr int CH = 8;

  int tid = threadIdx.x;
  int h = tid & (HID - 1);
  int d = tid >> LOGH;
  int nloc = blockIdx.x;
  int n = n0 + nloc;
  int col = d * HID + h;

  float vf = vv[2 * col], vr = vv[2 * col + 1];
  float bfv = bb[2 * col], brv = bb[2 * col + 1];
  float gc = 0.f, bc = 0.f;
  if (KK == 3) { gc = gln[col]; bc = bln[col]; }

  int t0 = d ? (T - 1) : 0;
  long long stp = d ? -1 : 1;
  long long ustr = stp * (long long)C;
  long long xstr = stp * (long long)DO;
  long long sstr = stp;

  const u16* Up = Uc + ((long long)nloc * T + t0) * C + d * (KK * HID) + h;
  const u16* Xp = X + ((long long)n * T + t0) * DO + col;
  const float2* Sp = (const float2*)stats + ((long long)n * T + t0);
  u16* Hp = H + ((long long)n * T + t0) * DO + col;

  u16 b0x[CH], b0f[CH], b0r[CH], b0s[CH];
  float b0m[CH], b0v[CH];
  u16 b1x[CH], b1f[CH], b1r[CH], b1s[CH];
  float b1m[CH], b1v[CH];
  float c = 0.f;

#define SCAN_LOAD(S, BX, BF, BR, BS, BM, BV)                        \
  {                                                                 \
    _Pragma("unroll") for (int i = 0; i < CH; ++i) {                \
      long long o = (long long)((S) + i) * ustr;                    \
      BX[i] = Up[o];                                                \
      BF[i] = Up[o + HID];                                          \
      BR[i] = Up[o + 2 * HID];                                      \
      if (KK == 4) {                                                \
        BS[i] = Up[o + 3 * HID];                                    \
      } else {                                                      \
        BS[i] = Xp[(long long)((S) + i) * xstr];                    \
        float2 stv = Sp[(long long)((S) + i) * sstr];               \
        BM[i] = stv.x;                                              \
        BV[i] = stv.y;                                              \
      }                                                             \
    }                                                               \
  }

#define SCAN_COMP(S, BX, BF, BR, BS, BM, BV)                        \
  {                                                                 \
    _Pragma("unroll") for (int i = 0; i < CH; ++i) {                \
      float xt = b2f(BX[i]), fr = b2f(BF[i]), rr = b2f(BR[i]);      \
      float res = (KK == 4) ? b2f(BS[i])                            \
                            : (b2f(BS[i]) - BM[i]) * BV[i] * gc + bc; \
      float ff = sigm(fr + vf * c + bfv);                           \
      float c2 = ff * c + (1.f - ff) * xt;                          \
      float rg = sigm(rr + vr * c + brv);                           \
      float hh = rg * fmaxf(c2, 0.f) + (1.f - rg) * res;            \
      c = c2;                                                       \
      Hp[(long long)((S) + i) * xstr] = f2b(hh);                    \
    }                                                               \
  }

  SCAN_LOAD(0, b0x, b0f, b0r, b0s, b0m, b0v);
  int s = 0;
  for (int it = 0; it < 31; ++it) {
    SCAN_LOAD(s + CH, b1x, b1f, b1r, b1s, b1m, b1v);
    SCAN_COMP(s, b0x, b0f, b0r, b0s, b0m, b0v);
    s += CH;
    SCAN_LOAD(s + CH, b0x, b0f, b0r, b0s, b0m, b0v);
    SCAN_COMP(s, b1x, b1f, b1r, b1s, b1m, b1v);
    s += CH;
  }
  SCAN_LOAD(s + CH, b1x, b1f, b1r, b1s, b1m, b1v);  // chunk 63
  SCAN_COMP(s, b0x, b0f, b0r, b0s, b0m, b0v);       // chunk 62
  s += CH;
  SCAN_COMP(s, b1x, b1f, b1r, b1s, b1m, b1v);       // chunk 63
#undef SCAN_LOAD
#undef SCAN_COMP
}

// ---------------- final projection: out[r, :] = h4[r, :] @ wout^T + bout (f32 out) ------
// (n,t) layout makes h4 rows == out rows. M=131072, K=128, N=64.
__global__ __launch_bounds__(256) void outgemm_kernel(const u16* __restrict__ h4,
                                                      const u16* __restrict__ wob,
                                                      const float* __restrict__ bout,
                                                      float* __restrict__ out) {
  __shared__ u16 As[128 * 128];  // 32 KiB
  int tid = threadIdx.x;
  int lane = tid & 63, wid = tid >> 6;
  int la = lane & 15, lq = lane >> 4;
  long long m0 = (long long)blockIdx.x * 128;

#pragma unroll
  for (int it = 0; it < 8; ++it) {
    int u = it * 256 + tid;
    int row = u >> 4, q = u & 15;
    const char* src = (const char*)h4 + (m0 + row) * 256 + ((q ^ (row & 7)) << 4);
    async16(src, (char*)As + it * 4096 + wid * 1024);
  }
  bf16x8 bfr[4][4];
#pragma unroll
  for (int nf = 0; nf < 4; ++nf)
#pragma unroll
    for (int ks = 0; ks < 4; ++ks)
      bfr[nf][ks] = *(const bf16x8*)&wob[(nf * 16 + la) * 128 + ks * 32 + lq * 8];
  __syncthreads();

  f32x4 acc[2][4] = {};
#pragma unroll
  for (int ks = 0; ks < 4; ++ks) {
#pragma unroll
    for (int mf = 0; mf < 2; ++mf) {
      int row = wid * 32 + mf * 16 + la;
      bf16x8 a = *(const bf16x8*)&As[row * 128 + (((ks * 4 + lq) ^ (row & 7)) << 3)];
#pragma unroll
      for (int nf = 0; nf < 4; ++nf)
        acc[mf][nf] = __builtin_amdgcn_mfma_f32_16x16x32_bf16(a, bfr[nf][ks], acc[mf][nf], 0, 0, 0);
    }
  }
#pragma unroll
  for (int mf = 0; mf < 2; ++mf)
#pragma unroll
    for (int nf = 0; nf < 4; ++nf) {
      int colg = nf * 16 + la;
      float bo = bout[colg];
#pragma unroll
      for (int reg = 0; reg < 4; ++reg) {
        long long r = m0 + wid * 32 + mf * 16 + lq * 4 + reg;
        out[r * 64 + colg] = acc[mf][nf][reg] + bo;
      }
    }
}

// ---------------- launch ----------------
extern "C" void kernel_launch(void* const* d_in, const int* in_sizes, int n_in,
                              void* d_out, int out_size, void* d_ws, size_t ws_size,
                              hipStream_t stream) {
  const int* x = (const int*)d_in[0];
  const float* emb = (const float*)d_in[1];
  const float* ng = (const float*)d_in[2];
  const float* nb = (const float*)d_in[3];
  const float* W[4] = {(const float*)d_in[4], (const float*)d_in[9], (const float*)d_in[14],
                       (const float*)d_in[19]};
  const float* Vv[4] = {(const float*)d_in[5], (const float*)d_in[10], (const float*)d_in[15],
                        (const float*)d_in[20]};
  const float* Bv[4] = {(const float*)d_in[6], (const float*)d_in[11], (const float*)d_in[16],
                        (const float*)d_in[21]};
  const float* G[4] = {(const float*)d_in[7], (const float*)d_in[12], (const float*)d_in[17],
                       (const float*)d_in[22]};
  const float* Bt[4] = {(const float*)d_in[8], (const float*)d_in[13], (const float*)d_in[18],
                        (const float*)d_in[23]};
  const float* wout = (const float*)d_in[24];
  const float* bout = (const float*)d_in[25];
  float* out = (float*)d_out;

  char* ws = (char*)d_ws;
  u16* XA = (u16*)ws;                       // 64 MiB ping
  u16* XB = (u16*)(ws + 67108864);          // 64 MiB pong
  float* stats = (float*)(ws + 134217728);  // 1 MiB
  char* p = ws + 135266304;
  u16* Wt[4];
  float* Sc[4];
  float* Tc[4];
  int Kd[4] = {256, 256, 256, 128};
  int Hd[4] = {128, 128, 64, 64};
  int kkv[4] = {3, 3, 4, 3};
  for (int i = 0; i < 4; ++i) {
    int C = 2 * Hd[i] * kkv[i];
    Wt[i] = (u16*)p; p += (size_t)C * Kd[i] * 2;
    Sc[i] = (float*)p; p += (size_t)C * 4;
    Tc[i] = (float*)p; p += (size_t)C * 4;
  }
  u16* wob = (u16*)p;                       // 16 KiB; ends < 137363456
  u16* Ubuf = (u16*)(ws + 137363456);

  // largest n-chunk NC (rows = NC*512, max C = 768) that fits in ws_size; cap 256.
  int NC = 256;
  while (NC > 4 &&
         137363456ull + (unsigned long long)NC * 512 * 768 * 2 > (unsigned long long)ws_size)
    NC >>= 1;

  prep_all_kernel<<<dim3(2464), dim3(256), 0, stream>>>(
      W[0], W[1], W[2], W[3], G[0], G[1], G[2], G[3], Bt[0], Bt[1], Bt[2], Bt[3], wout,
      Wt[0], Wt[1], Wt[2], Wt[3], Sc[0], Sc[1], Sc[2], Sc[3], Tc[0], Tc[1], Tc[2], Tc[3],
      wob);
  emb_kernel<<<dim3(32768), dim3(256), 0, stream>>>(x, emb, ng, nb, XA);

  // L1: XA -> XB  (K=256, C=768, HID=128, kk=3)
  for (int c = 0; c < 256; c += NC) {
    gemm_kernel<<<dim3(NC * 4, 6), dim3(256), 0, stream>>>(
        XA + (size_t)c * 512 * 256, Wt[0], stats + (size_t)c * 512 * 2, Sc[0], Tc[0], Ubuf, 256, 768);
    scan_kernel<3, 7><<<dim3(NC), dim3(256), 0, stream>>>(
        Ubuf, XA, stats, G[0], Bt[0], Vv[0], Bv[0], XB, c);
  }
  // L2: XB -> XA
  for (int c = 0; c < 256; c += NC) {
    gemm_kernel<<<dim3(NC * 4, 6), dim3(256), 0, stream>>>(
        XB + (size_t)c * 512 * 256, Wt[1], stats + (size_t)c * 512 * 2, Sc[1], Tc[1], Ubuf, 256, 768);
    scan_kernel<3, 7><<<dim3(NC), dim3(256), 0, stream>>>(
        Ubuf, XB, stats, G[1], Bt[1], Vv[1], Bv[1], XA, c);
  }
  // L3: XA -> XB  (K=256, C=512, HID=64, kk=4: res from U plane 3)
  for (int c = 0; c < 256; c += NC) {
    gemm_kernel<<<dim3(NC * 4, 4), dim3(256), 0, stream>>>(
        XA + (size_t)c * 512 * 256, Wt[2], stats + (size_t)c * 512 * 2, Sc[2], Tc[2], Ubuf, 256, 512);
    scan_kernel<4, 6><<<dim3(NC), dim3(128), 0, stream>>>(
        Ubuf, Ubuf, stats, G[2], Bt[2], Vv[2], Bv[2], XB, c);
  }
  // L4: XB -> XA  (K=128, C=384, HID=64, kk=3)
  for (int c = 0; c < 256; c += NC) {
    gemm_kernel<<<dim3(NC * 4, 3), dim3(256), 0, stream>>>(
        XB + (size_t)c * 512 * 128, Wt[3], stats + (size_t)c * 512 * 2, Sc[3], Tc[3], Ubuf, 128, 384);
    scan_kernel<3, 6><<<dim3(NC), dim3(128), 0, stream>>>(
        Ubuf, XB, stats, G[3], Bt[3], Vv[3], Bv[3], XA, c);
  }
  // output projection
  outgemm_kernel<<<dim3(1024), dim3(256), 0, stream>>>(XA, wob, bout, out);
}